// Round 3
// baseline (809.584 us; speedup 1.0000x reference)
//
#include <hip/hip_runtime.h>

#define SEQ   512
#define BATCH 4
#define NN    128
#define HID   64
#define G4    256   // 4*HID gates per layer

// Fast activations: v_exp_f32 + v_rcp_f32 (abs err ~1e-6, threshold is 1e-3)
__device__ __forceinline__ float frcp(float x)  { return __builtin_amdgcn_rcpf(x); }
__device__ __forceinline__ float fsigm(float x) { return frcp(1.f + __expf(-x)); }
__device__ __forceinline__ float ftanh(float x) { return 1.f - 2.f * frcp(1.f + __expf(2.f * x)); }
__device__ __forceinline__ float lrelu(float x) { return x > 0.f ? x : 0.2f * x; }
__device__ __forceinline__ float dot4f(float4 w, float4 h) {
  return fmaf(w.x, h.x, fmaf(w.y, h.y, fmaf(w.z, h.z, w.w * h.w)));
}
// quad_perm {1,2,3,0}: pull — lane j takes lane (j+1)&3 of its quad.
// After r applications, lane with quad-pos q holds the value originally at (q+r)&3.
__device__ __forceinline__ float rotq(float x) {
  int i = __float_as_int(x);
  i = __builtin_amdgcn_update_dpp(i, i, 0x39, 0xF, 0xF, false);
  return __int_as_float(i);
}
__device__ __forceinline__ void rotq4(float4& v) {
  v.x = rotq(v.x); v.y = rotq(v.y); v.z = rotq(v.z); v.w = rotq(v.w);
}

// ---------------------------------------------------------------------------
// prep_kernel (unchanged from R2, passed): blocks [0,128) X0 GEMM, [128,132) GAT.
// ---------------------------------------------------------------------------
__global__ __launch_bounds__(512) void prep_kernel(
    const float* __restrict__ x, const float* __restrict__ Wih0,
    const float* __restrict__ bih0, const float* __restrict__ bhh0,
    float* __restrict__ X0,
    const int* __restrict__ adj, const float* __restrict__ emb_w,
    const float* __restrict__ emb_b,
    const float* __restrict__ W1, const float* __restrict__ a1,
    const float* __restrict__ W2, const float* __restrict__ a2,
    float* __restrict__ xg_out)
{
  const int tid = threadIdx.x;
  if (blockIdx.x < 128) {
    __shared__ __align__(16) float xls[NN];
    const int g = tid >> 1, half = tid & 1;
    float4 w4[16];
    {
      const float4* wp = reinterpret_cast<const float4*>(Wih0 + g * NN + half * 64);
#pragma unroll
      for (int i = 0; i < 16; ++i) w4[i] = wp[i];
    }
    const float bsum = bih0[g] + bhh0[g];
    const int r0 = blockIdx.x * 16;
    for (int r = r0; r < r0 + 16; ++r) {
      const int tt = r >> 2, b = r & 3;
      if (tid < NN) xls[tid] = x[(b * SEQ + tt) * NN + tid];
      __syncthreads();
      const float4* hp = reinterpret_cast<const float4*>(&xls[half * 64]);
      float p0 = 0.f, p1 = 0.f, p2 = 0.f, p3 = 0.f;
#pragma unroll
      for (int k = 0; k < 16; k += 4) {
        p0 += dot4f(w4[k],     hp[k]);
        p1 += dot4f(w4[k + 1], hp[k + 1]);
        p2 += dot4f(w4[k + 2], hp[k + 2]);
        p3 += dot4f(w4[k + 3], hp[k + 3]);
      }
      float p = (p0 + p1) + (p2 + p3);
      p += __shfl_xor(p, 1);
      if (half == 0) X0[r * G4 + g] = p + bsum;
      __syncthreads();
    }
    return;
  }
  const int b = blockIdx.x - 128;
  __shared__ float adjm[NN * 129];
  __shared__ __align__(16) float xls[NN];
  __shared__ float u[16], v[16];
  __shared__ float Wh2[NN][9];
  __shared__ float f1b[NN], f2b[NN];
  __shared__ float p[NN];

  for (int idx = tid; idx < NN * NN; idx += 512)
    adjm[(idx >> 7) * 129 + (idx & 127)] = (adj[idx] > 0) ? 1.f : 0.f;
  if (tid < NN) xls[tid] = x[(b * SEQ + (SEQ - 1)) * NN + tid];
  if (tid < 16) {
    float uu = 0.f, vv = 0.f;
    for (int fp = 0; fp < 16; ++fp) {
      uu += emb_w[fp] * W1[fp * 16 + tid];
      vv += emb_b[fp] * W1[fp * 16 + tid];
    }
    u[tid] = uu; v[tid] = vv;
  }
  __syncthreads();
  float s1 = 0.f, t1 = 0.f, s2 = 0.f, t2 = 0.f;
  for (int f = 0; f < 16; ++f) {
    s1 += u[f] * a1[f];      t1 += v[f] * a1[f];
    s2 += u[f] * a1[16 + f]; t2 += v[f] * a1[16 + f];
  }
  if (tid < NN) {
    const int i = tid;
    const float f1i = xls[i] * s1 + t1;
    float m = -1e30f;
    for (int j = 0; j < NN; ++j)
      if (adjm[i * 129 + j] != 0.f)
        m = fmaxf(m, lrelu(f1i + xls[j] * s2 + t2));
    float ssum = 0.f, ps = 0.f;
    for (int j = 0; j < NN; ++j)
      if (adjm[i * 129 + j] != 0.f) {
        const float wgt = __expf(lrelu(f1i + xls[j] * s2 + t2) - m);
        ssum += wgt; ps += wgt * xls[j];
      }
    p[i] = ps / ssum;
  }
  __syncthreads();
  if (tid < NN) {
    const int i = tid;
    float xg1[16];
#pragma unroll
    for (int f = 0; f < 16; ++f) {
      const float ov = p[i] * u[f] + v[f];
      xg1[f] = ov > 0.f ? ov : expm1f(ov);
    }
    float wrow[8];
#pragma unroll
    for (int f2 = 0; f2 < 8; ++f2) wrow[f2] = 0.f;
#pragma unroll
    for (int f = 0; f < 16; ++f) {
      const float xv = xg1[f];
#pragma unroll
      for (int f2 = 0; f2 < 8; ++f2) wrow[f2] += xv * W2[f * 8 + f2];
    }
    float fb1 = 0.f, fb2 = 0.f;
#pragma unroll
    for (int f2 = 0; f2 < 8; ++f2) {
      Wh2[i][f2] = wrow[f2];
      fb1 += wrow[f2] * a2[f2];
      fb2 += wrow[f2] * a2[8 + f2];
    }
    f1b[i] = fb1; f2b[i] = fb2;
  }
  __syncthreads();
  if (tid < NN) {
    const int i = tid;
    const float fi = f1b[i];
    float m = -1e30f;
    for (int j = 0; j < NN; ++j)
      if (adjm[i * 129 + j] != 0.f)
        m = fmaxf(m, lrelu(fi + f2b[j]));
    float ssum = 0.f;
    float o[8];
#pragma unroll
    for (int f2 = 0; f2 < 8; ++f2) o[f2] = 0.f;
    for (int j = 0; j < NN; ++j)
      if (adjm[i * 129 + j] != 0.f) {
        const float wgt = __expf(lrelu(fi + f2b[j]) - m);
        ssum += wgt;
#pragma unroll
        for (int f2 = 0; f2 < 8; ++f2) o[f2] += wgt * Wh2[j][f2];
      }
    const float inv = 1.f / ssum;
#pragma unroll
    for (int f2 = 0; f2 < 8; ++f2)
      xg_out[b * (NN * 8) + i * 8 + f2] = o[f2] * inv;
  }
}

// ---------------------------------------------------------------------------
// lstm_heads: DPP-circulated 2-layer LSTM scan + fused heads.
// 4 blocks x 256 threads. Thread g owns L0 gate g (Whh0 row) and L1 gate g
// (Wih1 + Whh1 rows) = 192 pre-permuted weight floats in VGPRs.
// h is read once per wave as lane-distributed float4 slices and circulated
// by quad_perm DPP (VALU) — zero LDS broadcast traffic in the dot.
// amdgpu_waves_per_eu(1,1): pin allocator target to 1 wave/EU -> 512-VGPR
// budget -> no weight rematerialization (R1/R2 failure mode; only 4 blocks
// exist so occupancy is irrelevant).
// ---------------------------------------------------------------------------
__global__ __attribute__((amdgpu_waves_per_eu(1, 1))) __launch_bounds__(256)
void lstm_heads(
    const float* __restrict__ X0, const float* __restrict__ Whh0,
    const float* __restrict__ Wih1, const float* __restrict__ Whh1,
    const float* __restrict__ bih1, const float* __restrict__ bhh1,
    const float* __restrict__ xg,
    const float* __restrict__ dw1, const float* __restrict__ db1,
    const float* __restrict__ dw2, const float* __restrict__ db2,
    const float* __restrict__ rw1, const float* __restrict__ rb1,
    const float* __restrict__ rw2, const float* __restrict__ rb2,
    const float* __restrict__ vw1, const float* __restrict__ vb1,
    const float* __restrict__ vw2, const float* __restrict__ vb2,
    float* __restrict__ out)
{
  const int b   = blockIdx.x;
  const int tid = threadIdx.x;          // == gate id g, 0..255
  const int q2  = tid & 3;              // position within quad
  const int type = tid >> 6;            // 0:i 1:f 2:g(tanh) 3:o — wave-uniform

  __shared__ __align__(16) float pool[1824];
  float* h0s  = pool;          // 64
  float* h1s  = pool + 64;     // 64
  float* gact = pool + 128;    // 512
  float* cbuf = pool + 640;    // 1088
  float* hidc = pool + 1728;   // 96

  // Pre-permuted weights: for rotation r, this lane's hq[c].m holds
  // h[16c + 4*((q2+r)&3) + m], so load W[g][16c + 4*((q2+r)&3) + m].
  float4 wh0[4][4], wi1[4][4], wh1[4][4];
#pragma unroll
  for (int c = 0; c < 4; ++c)
#pragma unroll
    for (int r = 0; r < 4; ++r) {
      const int off = tid * 64 + 16 * c + 4 * ((q2 + r) & 3);
      wh0[c][r] = *reinterpret_cast<const float4*>(Whh0 + off);
      wi1[c][r] = *reinterpret_cast<const float4*>(Wih1 + off);
      wh1[c][r] = *reinterpret_cast<const float4*>(Whh1 + off);
    }
  const float b1sum = bih1[tid] + bhh1[tid];

  if (tid < 64) h0s[tid] = 0.f;
  else if (tid < 128) h1s[tid - 64] = 0.f;
  float cst = 0.f;                       // c0 (wave 0 lanes) / c1 (wave 1 lanes)
  float cur = X0[b * G4 + tid], nxt;     // X0 row for tt=0
  __syncthreads();

  for (int tt = 0; tt <= SEQ; ++tt) {
    // Prefetch next step's X0 (independent of the dots)
    const int nt = (tt + 1 < SEQ) ? (tt + 1) : (SEQ - 1);
    nxt = X0[(nt * BATCH + b) * G4 + tid];

    // Lane-distributed h slices: hq[c] = h[16c + 4*q2 .. +3]
    const float4* h0p = reinterpret_cast<const float4*>(h0s);
    const float4* h1p = reinterpret_cast<const float4*>(h1s);
    float4 hq0[4], hq1[4];
#pragma unroll
    for (int c = 0; c < 4; ++c) { hq0[c] = h0p[4 * c + q2]; hq1[c] = h1p[4 * c + q2]; }

    float a0a = cur, a0b = 0.f;          // L0: Whh0·h0 (+X0)
    float aAa = 0.f, aAb = 0.f;          // L1: Wih1·h0
    float aBa = 0.f, aBb = 0.f;          // L1: Whh1·h1
#pragma unroll
    for (int r = 0; r < 4; ++r) {
      a0a += dot4f(wh0[0][r], hq0[0]);  a0b += dot4f(wh0[1][r], hq0[1]);
      a0a += dot4f(wh0[2][r], hq0[2]);  a0b += dot4f(wh0[3][r], hq0[3]);
      aAa += dot4f(wi1[0][r], hq0[0]);  aAb += dot4f(wi1[1][r], hq0[1]);
      aAa += dot4f(wi1[2][r], hq0[2]);  aAb += dot4f(wi1[3][r], hq0[3]);
      aBa += dot4f(wh1[0][r], hq1[0]);  aBb += dot4f(wh1[1][r], hq1[1]);
      aBa += dot4f(wh1[2][r], hq1[2]);  aBb += dot4f(wh1[3][r], hq1[3]);
      if (r < 3) {
#pragma unroll
        for (int c = 0; c < 4; ++c) { rotq4(hq0[c]); rotq4(hq1[c]); }
      }
    }
    const float aL0 = a0a + a0b;
    const float aL1 = (aAa + aAb) + (aBa + aBb) + b1sum;
    gact[tid]       = (type == 2) ? ftanh(aL0) : fsigm(aL0);
    gact[256 + tid] = (type == 2) ? ftanh(aL1) : fsigm(aL1);
    __syncthreads();

    if (tid < 64) {                      // wave 0: layer-0 combine
      if (tt < SEQ) {
        const float i_ = gact[tid],       f_ = gact[64 + tid];
        const float gg = gact[128 + tid], o_ = gact[192 + tid];
        cst = fmaf(f_, cst, i_ * gg);
        h0s[tid] = o_ * ftanh(cst);
      }
    } else if (tid < 128) {              // wave 1: layer-1 combine (skewed)
      if (tt >= 1) {
        const int u = tid - 64;
        const float i_ = gact[256 + u], f_ = gact[320 + u];
        const float gg = gact[384 + u], o_ = gact[448 + u];
        cst = fmaf(f_, cst, i_ * gg);
        h1s[u] = o_ * ftanh(cst);
      }
    }
    cur = nxt;
    __syncthreads();
  }
  // h1s now holds h1[SEQ-1] = xl_out for this batch.

  // ---------------- fused heads: c = [h1(64) | xg_b(1024)] ----------------
  for (int k = tid; k < 1088; k += 256)
    cbuf[k] = (k < 64) ? h1s[k] : xg[b * 1024 + (k - 64)];
  __syncthreads();
  if (tid < 96) {
    const int head = tid >> 5, h = tid & 31;
    const float* w1 = (head == 0) ? dw1 : (head == 1) ? rw1 : vw1;
    const float* b1 = (head == 0) ? db1 : (head == 1) ? rb1 : vb1;
    float a0 = 0.f, a1v = 0.f, a2v = 0.f, a3v = 0.f;
    for (int k = 0; k < 1088; k += 4) {
      a0  = fmaf(cbuf[k],     w1[k * 32 + h],       a0);
      a1v = fmaf(cbuf[k + 1], w1[(k + 1) * 32 + h], a1v);
      a2v = fmaf(cbuf[k + 2], w1[(k + 2) * 32 + h], a2v);
      a3v = fmaf(cbuf[k + 3], w1[(k + 3) * 32 + h], a3v);
    }
    hidc[head * 32 + h] = fmaxf(b1[h] + ((a0 + a1v) + (a2v + a3v)), 0.f);
  }
  __syncthreads();
  if (tid < 4) {
    const int head2 = (tid < 2) ? tid : 2;
    const int o = (tid < 2) ? 0 : (tid - 2);
    const int odim = (tid < 2) ? 1 : 2;
    const float* w2  = (head2 == 0) ? dw2 : (head2 == 1) ? rw2 : vw2;
    const float* b2p = (head2 == 0) ? db2 : (head2 == 1) ? rb2 : vb2;
    float acc = b2p[o];
    for (int hh = 0; hh < 32; ++hh)
      acc = fmaf(hidc[head2 * 32 + hh], w2[hh * odim + o], acc);
    const int off = (tid == 0) ? b : (tid == 1) ? (4 + b) : (8 + 2 * b + o);
    out[off] = acc;   // [dir(4) | ret(4) | vol(4x2)] flat
  }
}

// ---------------------------------------------------------------------------
extern "C" void kernel_launch(void* const* d_in, const int* in_sizes, int n_in,
                              void* d_out, int out_size, void* d_ws, size_t ws_size,
                              hipStream_t stream) {
  const float* x     = (const float*)d_in[0];
  const int*   adj   = (const int*)  d_in[1];
  const float* emb_w = (const float*)d_in[2];
  const float* emb_b = (const float*)d_in[3];
  const float* g1W   = (const float*)d_in[4];
  const float* g1a   = (const float*)d_in[5];
  const float* g2W   = (const float*)d_in[6];
  const float* g2a   = (const float*)d_in[7];
  const float* Wih0  = (const float*)d_in[8];
  const float* Whh0  = (const float*)d_in[9];
  const float* bih0  = (const float*)d_in[10];
  const float* bhh0  = (const float*)d_in[11];
  const float* Wih1  = (const float*)d_in[12];
  const float* Whh1  = (const float*)d_in[13];
  const float* bih1  = (const float*)d_in[14];
  const float* bhh1  = (const float*)d_in[15];
  const float* dw1 = (const float*)d_in[16]; const float* db1 = (const float*)d_in[17];
  const float* dw2 = (const float*)d_in[18]; const float* db2 = (const float*)d_in[19];
  const float* rw1 = (const float*)d_in[20]; const float* rb1 = (const float*)d_in[21];
  const float* rw2 = (const float*)d_in[22]; const float* rb2 = (const float*)d_in[23];
  const float* vw1 = (const float*)d_in[24]; const float* vb1 = (const float*)d_in[25];
  const float* vw2 = (const float*)d_in[26]; const float* vb2 = (const float*)d_in[27];

  float* ws = (float*)d_ws;
  float* X0 = ws;                         // SEQ*BATCH*256 floats = 2 MB
  float* xg = ws + SEQ * BATCH * G4;      // 4096 floats
  float* out = (float*)d_out;

  hipLaunchKernelGGL(prep_kernel, dim3(132), dim3(512), 0, stream,
                     x, Wih0, bih0, bhh0, X0,
                     adj, emb_w, emb_b, g1W, g1a, g2W, g2a, xg);
  hipLaunchKernelGGL(lstm_heads, dim3(BATCH), dim3(256), 0, stream,
                     X0, Whh0, Wih1, Whh1, bih1, bhh1, xg,
                     dw1, db1, dw2, db2, rw1, rb1, rw2, rb2,
                     vw1, vb1, vw2, vb2, out);
}

// Round 4
// 611.469 us; speedup vs baseline: 1.3240x; 1.3240x over previous
//
#include <hip/hip_runtime.h>

#define SEQ   512
#define BATCH 4
#define NN    128
#define HID   64
#define G4    256   // 4*HID gates per layer

// Fast activations: v_exp_f32 + v_rcp_f32 (abs err ~1e-6, threshold is 1e-3)
__device__ __forceinline__ float frcp(float x)  { return __builtin_amdgcn_rcpf(x); }
__device__ __forceinline__ float fsigm(float x) { return frcp(1.f + __expf(-x)); }
__device__ __forceinline__ float ftanh(float x) { return 1.f - 2.f * frcp(1.f + __expf(2.f * x)); }
__device__ __forceinline__ float lrelu(float x) { return x > 0.f ? x : 0.2f * x; }
__device__ __forceinline__ float dot4f(float4 w, float4 h) {
  return fmaf(w.x, h.x, fmaf(w.y, h.y, fmaf(w.z, h.z, w.w * h.w)));
}
// Pin: make value opaque so RA cannot rematerialize the feeding load.
__device__ __forceinline__ void pin4(float4& v) {
  asm volatile("" : "+v"(v.x), "+v"(v.y), "+v"(v.z), "+v"(v.w));
}
// Quad butterfly sum via self-inverse quad_perm (direction-unambiguous):
// 0xB1 = {1,0,3,2} (xor1), 0x4E = {2,3,0,1} (xor2).
__device__ __forceinline__ float qsum(float x) {
  x += __int_as_float(__builtin_amdgcn_update_dpp(
      0, __float_as_int(x), 0xB1, 0xF, 0xF, true));
  x += __int_as_float(__builtin_amdgcn_update_dpp(
      0, __float_as_int(x), 0x4E, 0xF, 0xF, true));
  return x;
}
__device__ __forceinline__ float dotacc(const float4* w, const float4* h, float a) {
#pragma unroll
  for (int c = 0; c < 4; ++c) {
    a = fmaf(w[c].x, h[c].x, a);
    a = fmaf(w[c].y, h[c].y, a);
    a = fmaf(w[c].z, h[c].z, a);
    a = fmaf(w[c].w, h[c].w, a);
  }
  return a;
}

// ---------------------------------------------------------------------------
// prep_kernel: blocks [0,128) X0 GEMM (stores TRANSPOSED: per (t,b,unit) the
// 4 gate values i,f,g,o contiguous -> scan loads one dwordx4 per thread);
// blocks [128,132) GAT (unchanged, verified).
// ---------------------------------------------------------------------------
__global__ __launch_bounds__(512) void prep_kernel(
    const float* __restrict__ x, const float* __restrict__ Wih0,
    const float* __restrict__ bih0, const float* __restrict__ bhh0,
    float* __restrict__ X0,
    const int* __restrict__ adj, const float* __restrict__ emb_w,
    const float* __restrict__ emb_b,
    const float* __restrict__ W1, const float* __restrict__ a1,
    const float* __restrict__ W2, const float* __restrict__ a2,
    float* __restrict__ xg_out)
{
  const int tid = threadIdx.x;
  if (blockIdx.x < 128) {
    __shared__ __align__(16) float xls[NN];
    const int g = tid >> 1, half = tid & 1;
    float4 w4[16];
    {
      const float4* wp = reinterpret_cast<const float4*>(Wih0 + g * NN + half * 64);
#pragma unroll
      for (int i = 0; i < 16; ++i) w4[i] = wp[i];
    }
    const float bsum = bih0[g] + bhh0[g];
    const int r0 = blockIdx.x * 16;
    for (int r = r0; r < r0 + 16; ++r) {
      const int tt = r >> 2, b = r & 3;
      if (tid < NN) xls[tid] = x[(b * SEQ + tt) * NN + tid];
      __syncthreads();
      const float4* hp = reinterpret_cast<const float4*>(&xls[half * 64]);
      float p0 = 0.f, p1 = 0.f, p2 = 0.f, p3 = 0.f;
#pragma unroll
      for (int k = 0; k < 16; k += 4) {
        p0 += dot4f(w4[k],     hp[k]);
        p1 += dot4f(w4[k + 1], hp[k + 1]);
        p2 += dot4f(w4[k + 2], hp[k + 2]);
        p3 += dot4f(w4[k + 3], hp[k + 3]);
      }
      float p = (p0 + p1) + (p2 + p3);
      p += __shfl_xor(p, 1);
      // transposed store: row r, unit g&63, gate-type g>>6
      if (half == 0) X0[r * G4 + (g & 63) * 4 + (g >> 6)] = p + bsum;
      __syncthreads();
    }
    return;
  }
  const int b = blockIdx.x - 128;
  __shared__ float adjm[NN * 129];
  __shared__ __align__(16) float xls[NN];
  __shared__ float u[16], v[16];
  __shared__ float Wh2[NN][9];
  __shared__ float f1b[NN], f2b[NN];
  __shared__ float p[NN];

  for (int idx = tid; idx < NN * NN; idx += 512)
    adjm[(idx >> 7) * 129 + (idx & 127)] = (adj[idx] > 0) ? 1.f : 0.f;
  if (tid < NN) xls[tid] = x[(b * SEQ + (SEQ - 1)) * NN + tid];
  if (tid < 16) {
    float uu = 0.f, vv = 0.f;
    for (int fp = 0; fp < 16; ++fp) {
      uu += emb_w[fp] * W1[fp * 16 + tid];
      vv += emb_b[fp] * W1[fp * 16 + tid];
    }
    u[tid] = uu; v[tid] = vv;
  }
  __syncthreads();
  float s1 = 0.f, t1 = 0.f, s2 = 0.f, t2 = 0.f;
  for (int f = 0; f < 16; ++f) {
    s1 += u[f] * a1[f];      t1 += v[f] * a1[f];
    s2 += u[f] * a1[16 + f]; t2 += v[f] * a1[16 + f];
  }
  if (tid < NN) {
    const int i = tid;
    const float f1i = xls[i] * s1 + t1;
    float m = -1e30f;
    for (int j = 0; j < NN; ++j)
      if (adjm[i * 129 + j] != 0.f)
        m = fmaxf(m, lrelu(f1i + xls[j] * s2 + t2));
    float ssum = 0.f, ps = 0.f;
    for (int j = 0; j < NN; ++j)
      if (adjm[i * 129 + j] != 0.f) {
        const float wgt = __expf(lrelu(f1i + xls[j] * s2 + t2) - m);
        ssum += wgt; ps += wgt * xls[j];
      }
    p[i] = ps / ssum;
  }
  __syncthreads();
  if (tid < NN) {
    const int i = tid;
    float xg1[16];
#pragma unroll
    for (int f = 0; f < 16; ++f) {
      const float ov = p[i] * u[f] + v[f];
      xg1[f] = ov > 0.f ? ov : expm1f(ov);
    }
    float wrow[8];
#pragma unroll
    for (int f2 = 0; f2 < 8; ++f2) wrow[f2] = 0.f;
#pragma unroll
    for (int f = 0; f < 16; ++f) {
      const float xv = xg1[f];
#pragma unroll
      for (int f2 = 0; f2 < 8; ++f2) wrow[f2] += xv * W2[f * 8 + f2];
    }
    float fb1 = 0.f, fb2 = 0.f;
#pragma unroll
    for (int f2 = 0; f2 < 8; ++f2) {
      Wh2[i][f2] = wrow[f2];
      fb1 += wrow[f2] * a2[f2];
      fb2 += wrow[f2] * a2[8 + f2];
    }
    f1b[i] = fb1; f2b[i] = fb2;
  }
  __syncthreads();
  if (tid < NN) {
    const int i = tid;
    const float fi = f1b[i];
    float m = -1e30f;
    for (int j = 0; j < NN; ++j)
      if (adjm[i * 129 + j] != 0.f)
        m = fmaxf(m, lrelu(fi + f2b[j]));
    float ssum = 0.f;
    float o[8];
#pragma unroll
    for (int f2 = 0; f2 < 8; ++f2) o[f2] = 0.f;
    for (int j = 0; j < NN; ++j)
      if (adjm[i * 129 + j] != 0.f) {
        const float wgt = __expf(lrelu(fi + f2b[j]) - m);
        ssum += wgt;
#pragma unroll
        for (int f2 = 0; f2 < 8; ++f2) o[f2] += wgt * Wh2[j][f2];
      }
    const float inv = 1.f / ssum;
#pragma unroll
    for (int f2 = 0; f2 < 8; ++f2)
      xg_out[b * (NN * 8) + i * 8 + f2] = o[f2] * inv;
  }
}

// ---------------------------------------------------------------------------
// lstm_heads: unit-per-thread quad-butterfly 2-layer LSTM scan + fused heads.
// 4 blocks x 256 threads. Thread (u = tid>>2, q2 = tid&3) holds k-slice
// [16q2,16q2+16) of all 4 gate rows of unit u for Whh0/Wih1/Whh1 =
// 192 weight floats, asm-PINNED into VGPRs (R2/R3 failure: compiler
// rematerialized weight loads -> L1-BW-bound at ~3070 cyc/step).
// Partial dots reduced with self-inverse quad_perm butterflies (0xB1/0x4E);
// every lane then owns i,f,g,o of unit u for BOTH layers -> local cell
// update, no gact round-trip, double-buffered h, ONE barrier per step.
// ---------------------------------------------------------------------------
__global__ __attribute__((amdgpu_waves_per_eu(1, 1))) __launch_bounds__(256)
void lstm_heads(
    const float* __restrict__ X0T, const float* __restrict__ Whh0,
    const float* __restrict__ Wih1, const float* __restrict__ Whh1,
    const float* __restrict__ bih1, const float* __restrict__ bhh1,
    const float* __restrict__ xg,
    const float* __restrict__ dw1, const float* __restrict__ db1,
    const float* __restrict__ dw2, const float* __restrict__ db2,
    const float* __restrict__ rw1, const float* __restrict__ rb1,
    const float* __restrict__ rw2, const float* __restrict__ rb2,
    const float* __restrict__ vw1, const float* __restrict__ vb1,
    const float* __restrict__ vw2, const float* __restrict__ vb2,
    float* __restrict__ out)
{
  const int b  = blockIdx.x;
  const int t  = threadIdx.x;
  const int uu = t >> 2, q2 = t & 3;

  __shared__ __align__(16) float hb[2][2][HID];  // [buf][layer][unit]
  __shared__ float cbuf[1088];
  __shared__ float hidc[96];

  // Weights: w?[j][c] = M[unit + 64j][16*q2 + 4c .. +3]
  float4 w0[4][4], wA[4][4], wB[4][4];
#pragma unroll
  for (int j = 0; j < 4; ++j) {
    const int row = (uu + 64 * j) * HID + 16 * q2;
#pragma unroll
    for (int c = 0; c < 4; ++c) {
      w0[j][c] = *reinterpret_cast<const float4*>(Whh0 + row + 4 * c);
      wA[j][c] = *reinterpret_cast<const float4*>(Wih1 + row + 4 * c);
      wB[j][c] = *reinterpret_cast<const float4*>(Whh1 + row + 4 * c);
      pin4(w0[j][c]); pin4(wA[j][c]); pin4(wB[j][c]);
    }
  }
  float4 b1v;
  b1v.x = bih1[uu]       + bhh1[uu];
  b1v.y = bih1[uu + 64]  + bhh1[uu + 64];
  b1v.z = bih1[uu + 128] + bhh1[uu + 128];
  b1v.w = bih1[uu + 192] + bhh1[uu + 192];
  pin4(b1v);

  reinterpret_cast<float*>(hb)[t] = 0.f;   // 2*2*64 = 256 entries
  float cst0 = 0.f, cst1 = 0.f, h1last = 0.f;
  const float* X0b = X0T + b * G4 + uu * 4;
  float4 cur = *reinterpret_cast<const float4*>(X0b);   // row tt=0
  __syncthreads();

  for (int tt = 0; tt <= SEQ; ++tt) {
    const int rb = tt & 1, wb = rb ^ 1;
    const int nt = (tt + 1 < SEQ) ? (tt + 1) : (SEQ - 1);
    const float4 nxt = *reinterpret_cast<const float4*>(X0b + nt * (BATCH * G4));

    const float4* h0p = reinterpret_cast<const float4*>(&hb[rb][0][0]);
    const float4* h1p = reinterpret_cast<const float4*>(&hb[rb][1][0]);
    float4 hq0[4], hq1[4];
#pragma unroll
    for (int c = 0; c < 4; ++c) {
      hq0[c] = h0p[4 * q2 + c];
      hq1[c] = h1p[4 * q2 + c];
    }

    // 8 independent fmac chains (4x 16-deep L0, 4x 32-deep L1)
    float A0[4], A1[4];
#pragma unroll
    for (int j = 0; j < 4; ++j) {
      A0[j] = dotacc(w0[j], hq0, 0.f);
      A1[j] = dotacc(wB[j], hq1, dotacc(wA[j], hq0, 0.f));
    }

    // Layer 0: gates = qsum(partials) + X0 (full value, added post-reduce)
    const float g0i = fsigm(qsum(A0[0]) + cur.x);
    const float g0f = fsigm(qsum(A0[1]) + cur.y);
    const float g0g = ftanh(qsum(A0[2]) + cur.z);
    const float g0o = fsigm(qsum(A0[3]) + cur.w);
    cst0 = fmaf(g0f, cst0, g0i * g0g);
    const float h0new = g0o * ftanh(cst0);

    // Layer 1 (skewed: consumes h0[tt-1], h1[tt-2]; produces h1[tt-1])
    const float g1i = fsigm(qsum(A1[0]) + b1v.x);
    const float g1f = fsigm(qsum(A1[1]) + b1v.y);
    const float g1g = ftanh(qsum(A1[2]) + b1v.z);
    const float g1o = fsigm(qsum(A1[3]) + b1v.w);
    const float nc1 = fmaf(g1f, cst1, g1i * g1g);
    const float h1new = g1o * ftanh(nc1);
    const bool l1on = (tt >= 1);
    cst1 = l1on ? nc1 : cst1;
    const float h1w = l1on ? h1new : 0.f;

    hb[wb][0][uu] = h0new;   // 4 lanes, same addr, same value
    hb[wb][1][uu] = h1w;
    h1last = h1w;
    cur = nxt;
    __syncthreads();
  }
  // h1last = h1[SEQ-1] = xl_out[b][uu] (all lanes of the quad agree)

  // ---------------- fused heads: c = [h1(64) | xg_b(1024)] ----------------
  if (q2 == 0) cbuf[uu] = h1last;
  for (int k = t; k < 1024; k += 256) cbuf[64 + k] = xg[b * 1024 + k];
  __syncthreads();
  if (t < 96) {
    const int head = t >> 5, h = t & 31;
    const float* w1 = (head == 0) ? dw1 : (head == 1) ? rw1 : vw1;
    const float* b1 = (head == 0) ? db1 : (head == 1) ? rb1 : vb1;
    float a0 = 0.f, a1v = 0.f, a2v = 0.f, a3v = 0.f;
    for (int k = 0; k < 1088; k += 4) {
      a0  = fmaf(cbuf[k],     w1[k * 32 + h],       a0);
      a1v = fmaf(cbuf[k + 1], w1[(k + 1) * 32 + h], a1v);
      a2v = fmaf(cbuf[k + 2], w1[(k + 2) * 32 + h], a2v);
      a3v = fmaf(cbuf[k + 3], w1[(k + 3) * 32 + h], a3v);
    }
    hidc[head * 32 + h] = fmaxf(b1[h] + ((a0 + a1v) + (a2v + a3v)), 0.f);
  }
  __syncthreads();
  if (t < 4) {
    const int head2 = (t < 2) ? t : 2;
    const int o = (t < 2) ? 0 : (t - 2);
    const int odim = (t < 2) ? 1 : 2;
    const float* w2  = (head2 == 0) ? dw2 : (head2 == 1) ? rw2 : vw2;
    const float* b2p = (head2 == 0) ? db2 : (head2 == 1) ? rb2 : vb2;
    float acc = b2p[o];
    for (int hh = 0; hh < 32; ++hh)
      acc = fmaf(hidc[head2 * 32 + hh], w2[hh * odim + o], acc);
    const int off = (t == 0) ? b : (t == 1) ? (4 + b) : (8 + 2 * b + o);
    out[off] = acc;   // [dir(4) | ret(4) | vol(4x2)] flat
  }
}

// ---------------------------------------------------------------------------
extern "C" void kernel_launch(void* const* d_in, const int* in_sizes, int n_in,
                              void* d_out, int out_size, void* d_ws, size_t ws_size,
                              hipStream_t stream) {
  const float* x     = (const float*)d_in[0];
  const int*   adj   = (const int*)  d_in[1];
  const float* emb_w = (const float*)d_in[2];
  const float* emb_b = (const float*)d_in[3];
  const float* g1W   = (const float*)d_in[4];
  const float* g1a   = (const float*)d_in[5];
  const float* g2W   = (const float*)d_in[6];
  const float* g2a   = (const float*)d_in[7];
  const float* Wih0  = (const float*)d_in[8];
  const float* Whh0  = (const float*)d_in[9];
  const float* bih0  = (const float*)d_in[10];
  const float* bhh0  = (const float*)d_in[11];
  const float* Wih1  = (const float*)d_in[12];
  const float* Whh1  = (const float*)d_in[13];
  const float* bih1  = (const float*)d_in[14];
  const float* bhh1  = (const float*)d_in[15];
  const float* dw1 = (const float*)d_in[16]; const float* db1 = (const float*)d_in[17];
  const float* dw2 = (const float*)d_in[18]; const float* db2 = (const float*)d_in[19];
  const float* rw1 = (const float*)d_in[20]; const float* rb1 = (const float*)d_in[21];
  const float* rw2 = (const float*)d_in[22]; const float* rb2 = (const float*)d_in[23];
  const float* vw1 = (const float*)d_in[24]; const float* vb1 = (const float*)d_in[25];
  const float* vw2 = (const float*)d_in[26]; const float* vb2 = (const float*)d_in[27];

  float* ws = (float*)d_ws;
  float* X0 = ws;                         // SEQ*BATCH*256 floats = 2 MB (transposed layout)
  float* xg = ws + SEQ * BATCH * G4;      // 4096 floats
  float* out = (float*)d_out;

  hipLaunchKernelGGL(prep_kernel, dim3(132), dim3(512), 0, stream,
                     x, Wih0, bih0, bhh0, X0,
                     adj, emb_w, emb_b, g1W, g1a, g2W, g2a, xg);
  hipLaunchKernelGGL(lstm_heads, dim3(BATCH), dim3(256), 0, stream,
                     X0, Whh0, Wih1, Whh1, bih1, bhh1, xg,
                     dw1, db1, dw2, db2, rw1, rb1, rw2, rb2,
                     vw1, vb1, vw2, vb2, out);
}

// Round 5
// 519.419 us; speedup vs baseline: 1.5586x; 1.1772x over previous
//
#include <hip/hip_runtime.h>

#define SEQ   512
#define BATCH 4
#define NN    128
#define HID   64
#define G4    256   // 4*HID gates per layer

// Fast activations: v_exp_f32 + v_rcp_f32 (abs err ~1e-6, threshold is 1e-3)
__device__ __forceinline__ float frcp(float x)  { return __builtin_amdgcn_rcpf(x); }
__device__ __forceinline__ float fsigm(float x) { return frcp(1.f + __expf(-x)); }
__device__ __forceinline__ float ftanh(float x) { return 1.f - 2.f * frcp(1.f + __expf(2.f * x)); }
__device__ __forceinline__ float lrelu(float x) { return x > 0.f ? x : 0.2f * x; }
__device__ __forceinline__ float dot4f(float4 w, float4 h) {
  return fmaf(w.x, h.x, fmaf(w.y, h.y, fmaf(w.z, h.z, w.w * h.w)));
}
// Pin: forces the 4 components to live in VGPRs HERE. Used INSIDE the loop:
// the values become loop-carried asm-redefinitions -> cannot be
// rematerialized, and spilling would cost a store+load per iteration, so
// the RA keeps them resident (R2/R3/R4 failure: init-only pins were spilled
// to scratch and re-loaded every step -> L1-BW bound at ~2100 cyc/step).
__device__ __forceinline__ void pin4(float4& v) {
  asm volatile("" : "+v"(v.x), "+v"(v.y), "+v"(v.z), "+v"(v.w));
}
// Quad butterfly sum via self-inverse quad_perm: 0xB1={1,0,3,2}, 0x4E={2,3,0,1}.
__device__ __forceinline__ float qsum(float x) {
  x += __int_as_float(__builtin_amdgcn_update_dpp(
      0, __float_as_int(x), 0xB1, 0xF, 0xF, true));
  x += __int_as_float(__builtin_amdgcn_update_dpp(
      0, __float_as_int(x), 0x4E, 0xF, 0xF, true));
  return x;
}
__device__ __forceinline__ float dotacc(const float4* w, const float4* h, float a) {
#pragma unroll
  for (int c = 0; c < 4; ++c) {
    a = fmaf(w[c].x, h[c].x, a);
    a = fmaf(w[c].y, h[c].y, a);
    a = fmaf(w[c].z, h[c].z, a);
    a = fmaf(w[c].w, h[c].w, a);
  }
  return a;
}

// ---------------------------------------------------------------------------
// prep_kernel (verified R4): blocks [0,128) X0 GEMM (transposed store:
// (t,b,unit) -> 4 contiguous gate values i,f,g,o); blocks [128,132) GAT.
// ---------------------------------------------------------------------------
__global__ __launch_bounds__(512) void prep_kernel(
    const float* __restrict__ x, const float* __restrict__ Wih0,
    const float* __restrict__ bih0, const float* __restrict__ bhh0,
    float* __restrict__ X0,
    const int* __restrict__ adj, const float* __restrict__ emb_w,
    const float* __restrict__ emb_b,
    const float* __restrict__ W1, const float* __restrict__ a1,
    const float* __restrict__ W2, const float* __restrict__ a2,
    float* __restrict__ xg_out)
{
  const int tid = threadIdx.x;
  if (blockIdx.x < 128) {
    __shared__ __align__(16) float xls[NN];
    const int g = tid >> 1, half = tid & 1;
    float4 w4[16];
    {
      const float4* wp = reinterpret_cast<const float4*>(Wih0 + g * NN + half * 64);
#pragma unroll
      for (int i = 0; i < 16; ++i) w4[i] = wp[i];
    }
    const float bsum = bih0[g] + bhh0[g];
    const int r0 = blockIdx.x * 16;
    for (int r = r0; r < r0 + 16; ++r) {
      const int tt = r >> 2, b = r & 3;
      if (tid < NN) xls[tid] = x[(b * SEQ + tt) * NN + tid];
      __syncthreads();
      const float4* hp = reinterpret_cast<const float4*>(&xls[half * 64]);
      float p0 = 0.f, p1 = 0.f, p2 = 0.f, p3 = 0.f;
#pragma unroll
      for (int k = 0; k < 16; k += 4) {
        p0 += dot4f(w4[k],     hp[k]);
        p1 += dot4f(w4[k + 1], hp[k + 1]);
        p2 += dot4f(w4[k + 2], hp[k + 2]);
        p3 += dot4f(w4[k + 3], hp[k + 3]);
      }
      float p = (p0 + p1) + (p2 + p3);
      p += __shfl_xor(p, 1);
      if (half == 0) X0[r * G4 + (g & 63) * 4 + (g >> 6)] = p + bsum;
      __syncthreads();
    }
    return;
  }
  const int b = blockIdx.x - 128;
  __shared__ float adjm[NN * 129];
  __shared__ __align__(16) float xls[NN];
  __shared__ float u[16], v[16];
  __shared__ float Wh2[NN][9];
  __shared__ float f1b[NN], f2b[NN];
  __shared__ float p[NN];

  for (int idx = tid; idx < NN * NN; idx += 512)
    adjm[(idx >> 7) * 129 + (idx & 127)] = (adj[idx] > 0) ? 1.f : 0.f;
  if (tid < NN) xls[tid] = x[(b * SEQ + (SEQ - 1)) * NN + tid];
  if (tid < 16) {
    float uu = 0.f, vv = 0.f;
    for (int fp = 0; fp < 16; ++fp) {
      uu += emb_w[fp] * W1[fp * 16 + tid];
      vv += emb_b[fp] * W1[fp * 16 + tid];
    }
    u[tid] = uu; v[tid] = vv;
  }
  __syncthreads();
  float s1 = 0.f, t1 = 0.f, s2 = 0.f, t2 = 0.f;
  for (int f = 0; f < 16; ++f) {
    s1 += u[f] * a1[f];      t1 += v[f] * a1[f];
    s2 += u[f] * a1[16 + f]; t2 += v[f] * a1[16 + f];
  }
  if (tid < NN) {
    const int i = tid;
    const float f1i = xls[i] * s1 + t1;
    float m = -1e30f;
    for (int j = 0; j < NN; ++j)
      if (adjm[i * 129 + j] != 0.f)
        m = fmaxf(m, lrelu(f1i + xls[j] * s2 + t2));
    float ssum = 0.f, ps = 0.f;
    for (int j = 0; j < NN; ++j)
      if (adjm[i * 129 + j] != 0.f) {
        const float wgt = __expf(lrelu(f1i + xls[j] * s2 + t2) - m);
        ssum += wgt; ps += wgt * xls[j];
      }
    p[i] = ps / ssum;
  }
  __syncthreads();
  if (tid < NN) {
    const int i = tid;
    float xg1[16];
#pragma unroll
    for (int f = 0; f < 16; ++f) {
      const float ov = p[i] * u[f] + v[f];
      xg1[f] = ov > 0.f ? ov : expm1f(ov);
    }
    float wrow[8];
#pragma unroll
    for (int f2 = 0; f2 < 8; ++f2) wrow[f2] = 0.f;
#pragma unroll
    for (int f = 0; f < 16; ++f) {
      const float xv = xg1[f];
#pragma unroll
      for (int f2 = 0; f2 < 8; ++f2) wrow[f2] += xv * W2[f * 8 + f2];
    }
    float fb1 = 0.f, fb2 = 0.f;
#pragma unroll
    for (int f2 = 0; f2 < 8; ++f2) {
      Wh2[i][f2] = wrow[f2];
      fb1 += wrow[f2] * a2[f2];
      fb2 += wrow[f2] * a2[8 + f2];
    }
    f1b[i] = fb1; f2b[i] = fb2;
  }
  __syncthreads();
  if (tid < NN) {
    const int i = tid;
    const float fi = f1b[i];
    float m = -1e30f;
    for (int j = 0; j < NN; ++j)
      if (adjm[i * 129 + j] != 0.f)
        m = fmaxf(m, lrelu(fi + f2b[j]));
    float ssum = 0.f;
    float o[8];
#pragma unroll
    for (int f2 = 0; f2 < 8; ++f2) o[f2] = 0.f;
    for (int j = 0; j < NN; ++j)
      if (adjm[i * 129 + j] != 0.f) {
        const float wgt = __expf(lrelu(fi + f2b[j]) - m);
        ssum += wgt;
#pragma unroll
        for (int f2 = 0; f2 < 8; ++f2) o[f2] += wgt * Wh2[j][f2];
      }
    const float inv = 1.f / ssum;
#pragma unroll
    for (int f2 = 0; f2 < 8; ++f2)
      xg_out[b * (NN * 8) + i * 8 + f2] = o[f2] * inv;
  }
}

// ---------------------------------------------------------------------------
// lstm_heads: 3-group quad-butterfly 2-layer LSTM scan + fused heads.
// 4 blocks x 768 threads (12 waves, 3/SIMD). Thread (group, u=r>>2, q2=r&3):
//   group0: Whh0[u+64j][16q2..+16)  -> L0 gates, owns c0, writes h0
//   group1: Wih1[u+64j][16q2..+16)  -> L1 ih-partials -> P1 in LDS
//   group2: Whh1[u+64j][16q2..+16)  -> L1 hh-partials + P1 + bias, owns c1
// Exactly 64 weight floats/thread, pinned IN-LOOP (see pin4). Double-buffered
// h, 2 barriers/step. L1 skewed one step behind L0.
// ---------------------------------------------------------------------------
__global__ __launch_bounds__(768, 3)
void lstm_heads(
    const float* __restrict__ X0T, const float* __restrict__ Whh0,
    const float* __restrict__ Wih1, const float* __restrict__ Whh1,
    const float* __restrict__ bih1, const float* __restrict__ bhh1,
    const float* __restrict__ xg,
    const float* __restrict__ dw1, const float* __restrict__ db1,
    const float* __restrict__ dw2, const float* __restrict__ db2,
    const float* __restrict__ rw1, const float* __restrict__ rb1,
    const float* __restrict__ rw2, const float* __restrict__ rb2,
    const float* __restrict__ vw1, const float* __restrict__ vb1,
    const float* __restrict__ vw2, const float* __restrict__ vb2,
    float* __restrict__ out)
{
  const int b   = blockIdx.x;
  const int t   = threadIdx.x;
  const int grp = t >> 8;            // 0,1,2 (wave-aligned: 4 waves each)
  const int r   = t & 255;
  const int uu  = r >> 2, q2 = r & 3;

  __shared__ __align__(16) float hb[2][2][HID];   // [buf][layer][unit]
  __shared__ __align__(16) float P1[G4];          // L1 ih-partials [unit*4+gate]
  __shared__ float cbuf[1088];
  __shared__ float hidc[96];

  // 16 float4 of weights per thread
  const float* Wsrc = (grp == 0) ? Whh0 : (grp == 1) ? Wih1 : Whh1;
  float4 w[4][4];
#pragma unroll
  for (int j = 0; j < 4; ++j) {
    const int row = (uu + 64 * j) * HID + 16 * q2;
#pragma unroll
    for (int c = 0; c < 4; ++c)
      w[j][c] = *reinterpret_cast<const float4*>(Wsrc + row + 4 * c);
  }
  float4 b1v = make_float4(0.f, 0.f, 0.f, 0.f);
  if (grp == 2) {
    b1v.x = bih1[uu]       + bhh1[uu];
    b1v.y = bih1[uu + 64]  + bhh1[uu + 64];
    b1v.z = bih1[uu + 128] + bhh1[uu + 128];
    b1v.w = bih1[uu + 192] + bhh1[uu + 192];
  }

  if (t < 256) reinterpret_cast<float*>(hb)[t] = 0.f;
  float cst = 0.f;                    // c0 (grp0) / c1 (grp2), redundant per quad
  const float* X0b = X0T + b * G4 + uu * 4;
  float4 cur = make_float4(0.f, 0.f, 0.f, 0.f);
  if (grp == 0) cur = *reinterpret_cast<const float4*>(X0b);
  __syncthreads();

  for (int tt = 0; tt <= SEQ; ++tt) {
    // In-loop pins: weights are asm-redefined every iteration.
#pragma unroll
    for (int j = 0; j < 4; ++j) {
      pin4(w[j][0]); pin4(w[j][1]); pin4(w[j][2]); pin4(w[j][3]);
    }
    const int rb = tt & 1, wb = rb ^ 1;
    const bool on0 = (grp == 0) && (tt < SEQ);
    const bool on12 = (grp != 0) && (tt >= 1);

    // h source: grp0/grp1 read h0[tt-1]; grp2 reads h1[tt-2]
    const float4* hp = reinterpret_cast<const float4*>(
        (grp == 2) ? &hb[rb][1][0] : &hb[rb][0][0]);
    float4 hq[4];
#pragma unroll
    for (int c = 0; c < 4; ++c) hq[c] = hp[4 * q2 + c];

    float4 nxt = cur;
    if (on0) {
      const int nt = (tt + 1 < SEQ) ? (tt + 1) : (SEQ - 1);
      nxt = *reinterpret_cast<const float4*>(X0b + nt * (BATCH * G4));
    }

    // 4 independent 16-deep fmac chains, then quad-butterfly reduce
    float S0, S1, S2, S3;
    {
      float A0 = dotacc(w[0], hq, 0.f);
      float A1 = dotacc(w[1], hq, 0.f);
      float A2 = dotacc(w[2], hq, 0.f);
      float A3 = dotacc(w[3], hq, 0.f);
      S0 = qsum(A0); S1 = qsum(A1); S2 = qsum(A2); S3 = qsum(A3);
    }

    if (on0) {                        // layer 0: finish gates, update c0, h0
      const float gi = fsigm(S0 + cur.x);
      const float gf = fsigm(S1 + cur.y);
      const float gg = ftanh(S2 + cur.z);
      const float go = fsigm(S3 + cur.w);
      cst = fmaf(gf, cst, gi * gg);
      hb[wb][0][uu] = go * ftanh(cst);   // 4 lanes, same addr, same value
    } else if (grp == 1 && tt >= 1) {    // L1 ih-partials -> LDS
      const float sel = (q2 == 0) ? S0 : (q2 == 1) ? S1 : (q2 == 2) ? S2 : S3;
      P1[uu * 4 + q2] = sel;
    }
    __syncthreads();                  // barrier A: P1 visible, all rb reads done

    if (grp == 2) {
      if (tt >= 1) {
        const float4 p1 = *reinterpret_cast<const float4*>(&P1[uu * 4]);
        const float gi = fsigm(S0 + p1.x + b1v.x);
        const float gf = fsigm(S1 + p1.y + b1v.y);
        const float gg = ftanh(S2 + p1.z + b1v.z);
        const float go = fsigm(S3 + p1.w + b1v.w);
        cst = fmaf(gf, cst, gi * gg);
        hb[wb][1][uu] = go * ftanh(cst);
      }
    }
    cur = nxt;
    __syncthreads();                  // barrier B: h writes visible
  }
  // final h1 = h1[SEQ-1] sits in hb[1][1][*]  (SEQ even -> last write buf=1)

  // ---------------- fused heads: c = [h1(64) | xg_b(1024)] ----------------
  if (t < 64) cbuf[t] = hb[1][1][t];
  for (int k = t; k < 1024; k += 768) cbuf[64 + k] = xg[b * 1024 + k];
  __syncthreads();
  if (t < 96) {
    const int head = t >> 5, h = t & 31;
    const float* w1 = (head == 0) ? dw1 : (head == 1) ? rw1 : vw1;
    const float* b1 = (head == 0) ? db1 : (head == 1) ? rb1 : vb1;
    float a0 = 0.f, a1v = 0.f, a2v = 0.f, a3v = 0.f;
    for (int k = 0; k < 1088; k += 4) {
      a0  = fmaf(cbuf[k],     w1[k * 32 + h],       a0);
      a1v = fmaf(cbuf[k + 1], w1[(k + 1) * 32 + h], a1v);
      a2v = fmaf(cbuf[k + 2], w1[(k + 2) * 32 + h], a2v);
      a3v = fmaf(cbuf[k + 3], w1[(k + 3) * 32 + h], a3v);
    }
    hidc[head * 32 + h] = fmaxf(b1[h] + ((a0 + a1v) + (a2v + a3v)), 0.f);
  }
  __syncthreads();
  if (t < 4) {
    const int head2 = (t < 2) ? t : 2;
    const int o = (t < 2) ? 0 : (t - 2);
    const int odim = (t < 2) ? 1 : 2;
    const float* w2  = (head2 == 0) ? dw2 : (head2 == 1) ? rw2 : vw2;
    const float* b2p = (head2 == 0) ? db2 : (head2 == 1) ? rb2 : vb2;
    float acc = b2p[o];
    for (int hh = 0; hh < 32; ++hh)
      acc = fmaf(hidc[head2 * 32 + hh], w2[hh * odim + o], acc);
    const int off = (t == 0) ? b : (t == 1) ? (4 + b) : (8 + 2 * b + o);
    out[off] = acc;   // [dir(4) | ret(4) | vol(4x2)] flat
  }
}

// ---------------------------------------------------------------------------
extern "C" void kernel_launch(void* const* d_in, const int* in_sizes, int n_in,
                              void* d_out, int out_size, void* d_ws, size_t ws_size,
                              hipStream_t stream) {
  const float* x     = (const float*)d_in[0];
  const int*   adj   = (const int*)  d_in[1];
  const float* emb_w = (const float*)d_in[2];
  const float* emb_b = (const float*)d_in[3];
  const float* g1W   = (const float*)d_in[4];
  const float* g1a   = (const float*)d_in[5];
  const float* g2W   = (const float*)d_in[6];
  const float* g2a   = (const float*)d_in[7];
  const float* Wih0  = (const float*)d_in[8];
  const float* Whh0  = (const float*)d_in[9];
  const float* bih0  = (const float*)d_in[10];
  const float* bhh0  = (const float*)d_in[11];
  const float* Wih1  = (const float*)d_in[12];
  const float* Whh1  = (const float*)d_in[13];
  const float* bih1  = (const float*)d_in[14];
  const float* bhh1  = (const float*)d_in[15];
  const float* dw1 = (const float*)d_in[16]; const float* db1 = (const float*)d_in[17];
  const float* dw2 = (const float*)d_in[18]; const float* db2 = (const float*)d_in[19];
  const float* rw1 = (const float*)d_in[20]; const float* rb1 = (const float*)d_in[21];
  const float* rw2 = (const float*)d_in[22]; const float* rb2 = (const float*)d_in[23];
  const float* vw1 = (const float*)d_in[24]; const float* vb1 = (const float*)d_in[25];
  const float* vw2 = (const float*)d_in[26]; const float* vb2 = (const float*)d_in[27];

  float* ws = (float*)d_ws;
  float* X0 = ws;                         // SEQ*BATCH*256 floats = 2 MB (transposed)
  float* xg = ws + SEQ * BATCH * G4;      // 4096 floats
  float* out = (float*)d_out;

  hipLaunchKernelGGL(prep_kernel, dim3(132), dim3(512), 0, stream,
                     x, Wih0, bih0, bhh0, X0,
                     adj, emb_w, emb_b, g1W, g1a, g2W, g2a, xg);
  hipLaunchKernelGGL(lstm_heads, dim3(BATCH), dim3(768), 0, stream,
                     X0, Whh0, Wih1, Whh1, bih1, bhh1, xg,
                     dw1, db1, dw2, db2, rw1, rb1, rw2, rb2,
                     vw1, vb1, vw2, vb2, out);
}

// Round 6
// 469.648 us; speedup vs baseline: 1.7238x; 1.1060x over previous
//
#include <hip/hip_runtime.h>

#define SEQ   512
#define BATCH 4
#define NN    128
#define HID   64
#define G4    256   // 4*HID gates per layer

// Fast activations: v_exp_f32 + v_rcp_f32 (abs err ~1e-6, threshold is 1e-3)
__device__ __forceinline__ float frcp(float x)  { return __builtin_amdgcn_rcpf(x); }
__device__ __forceinline__ float fsigm(float x) { return frcp(1.f + __expf(-x)); }
__device__ __forceinline__ float ftanh(float x) { return 1.f - 2.f * frcp(1.f + __expf(2.f * x)); }
__device__ __forceinline__ float lrelu(float x) { return x > 0.f ? x : 0.2f * x; }
__device__ __forceinline__ float dot4f(float4 w, float4 h) {
  return fmaf(w.x, h.x, fmaf(w.y, h.y, fmaf(w.z, h.z, w.w * h.w)));
}
// Init-time pin: block load-sinking into the loop. NOT used in-loop (R5
// showed in-loop pins cause per-iteration scratch store+load churn).
__device__ __forceinline__ void pin4(float4& v) {
  asm volatile("" : "+v"(v.x), "+v"(v.y), "+v"(v.z), "+v"(v.w));
}
// Quad butterfly sum via self-inverse quad_perm: 0xB1={1,0,3,2}, 0x4E={2,3,0,1}.
__device__ __forceinline__ float qsum(float x) {
  x += __int_as_float(__builtin_amdgcn_update_dpp(
      0, __float_as_int(x), 0xB1, 0xF, 0xF, true));
  x += __int_as_float(__builtin_amdgcn_update_dpp(
      0, __float_as_int(x), 0x4E, 0xF, 0xF, true));
  return x;
}
__device__ __forceinline__ float dotacc(const float4* w, const float4* h, float a) {
#pragma unroll
  for (int c = 0; c < 4; ++c) {
    a = fmaf(w[c].x, h[c].x, a);
    a = fmaf(w[c].y, h[c].y, a);
    a = fmaf(w[c].z, h[c].z, a);
    a = fmaf(w[c].w, h[c].w, a);
  }
  return a;
}

// ---------------------------------------------------------------------------
// prep_kernel (verified R4/R5): blocks [0,128) X0 GEMM (transposed store:
// (t,b,unit) -> 4 contiguous gate values i,f,g,o); blocks [128,132) GAT.
// ---------------------------------------------------------------------------
__global__ __launch_bounds__(512) void prep_kernel(
    const float* __restrict__ x, const float* __restrict__ Wih0,
    const float* __restrict__ bih0, const float* __restrict__ bhh0,
    float* __restrict__ X0,
    const int* __restrict__ adj, const float* __restrict__ emb_w,
    const float* __restrict__ emb_b,
    const float* __restrict__ W1, const float* __restrict__ a1,
    const float* __restrict__ W2, const float* __restrict__ a2,
    float* __restrict__ xg_out)
{
  const int tid = threadIdx.x;
  if (blockIdx.x < 128) {
    __shared__ __align__(16) float xls[NN];
    const int g = tid >> 1, half = tid & 1;
    float4 w4[16];
    {
      const float4* wp = reinterpret_cast<const float4*>(Wih0 + g * NN + half * 64);
#pragma unroll
      for (int i = 0; i < 16; ++i) w4[i] = wp[i];
    }
    const float bsum = bih0[g] + bhh0[g];
    const int r0 = blockIdx.x * 16;
    for (int r = r0; r < r0 + 16; ++r) {
      const int tt = r >> 2, b = r & 3;
      if (tid < NN) xls[tid] = x[(b * SEQ + tt) * NN + tid];
      __syncthreads();
      const float4* hp = reinterpret_cast<const float4*>(&xls[half * 64]);
      float p0 = 0.f, p1 = 0.f, p2 = 0.f, p3 = 0.f;
#pragma unroll
      for (int k = 0; k < 16; k += 4) {
        p0 += dot4f(w4[k],     hp[k]);
        p1 += dot4f(w4[k + 1], hp[k + 1]);
        p2 += dot4f(w4[k + 2], hp[k + 2]);
        p3 += dot4f(w4[k + 3], hp[k + 3]);
      }
      float p = (p0 + p1) + (p2 + p3);
      p += __shfl_xor(p, 1);
      if (half == 0) X0[r * G4 + (g & 63) * 4 + (g >> 6)] = p + bsum;
      __syncthreads();
    }
    return;
  }
  const int b = blockIdx.x - 128;
  __shared__ float adjm[NN * 129];
  __shared__ __align__(16) float xls[NN];
  __shared__ float u[16], v[16];
  __shared__ float Wh2[NN][9];
  __shared__ float f1b[NN], f2b[NN];
  __shared__ float p[NN];

  for (int idx = tid; idx < NN * NN; idx += 512)
    adjm[(idx >> 7) * 129 + (idx & 127)] = (adj[idx] > 0) ? 1.f : 0.f;
  if (tid < NN) xls[tid] = x[(b * SEQ + (SEQ - 1)) * NN + tid];
  if (tid < 16) {
    float uu = 0.f, vv = 0.f;
    for (int fp = 0; fp < 16; ++fp) {
      uu += emb_w[fp] * W1[fp * 16 + tid];
      vv += emb_b[fp] * W1[fp * 16 + tid];
    }
    u[tid] = uu; v[tid] = vv;
  }
  __syncthreads();
  float s1 = 0.f, t1 = 0.f, s2 = 0.f, t2 = 0.f;
  for (int f = 0; f < 16; ++f) {
    s1 += u[f] * a1[f];      t1 += v[f] * a1[f];
    s2 += u[f] * a1[16 + f]; t2 += v[f] * a1[16 + f];
  }
  if (tid < NN) {
    const int i = tid;
    const float f1i = xls[i] * s1 + t1;
    float m = -1e30f;
    for (int j = 0; j < NN; ++j)
      if (adjm[i * 129 + j] != 0.f)
        m = fmaxf(m, lrelu(f1i + xls[j] * s2 + t2));
    float ssum = 0.f, ps = 0.f;
    for (int j = 0; j < NN; ++j)
      if (adjm[i * 129 + j] != 0.f) {
        const float wgt = __expf(lrelu(f1i + xls[j] * s2 + t2) - m);
        ssum += wgt; ps += wgt * xls[j];
      }
    p[i] = ps / ssum;
  }
  __syncthreads();
  if (tid < NN) {
    const int i = tid;
    float xg1[16];
#pragma unroll
    for (int f = 0; f < 16; ++f) {
      const float ov = p[i] * u[f] + v[f];
      xg1[f] = ov > 0.f ? ov : expm1f(ov);
    }
    float wrow[8];
#pragma unroll
    for (int f2 = 0; f2 < 8; ++f2) wrow[f2] = 0.f;
#pragma unroll
    for (int f = 0; f < 16; ++f) {
      const float xv = xg1[f];
#pragma unroll
      for (int f2 = 0; f2 < 8; ++f2) wrow[f2] += xv * W2[f * 8 + f2];
    }
    float fb1 = 0.f, fb2 = 0.f;
#pragma unroll
    for (int f2 = 0; f2 < 8; ++f2) {
      Wh2[i][f2] = wrow[f2];
      fb1 += wrow[f2] * a2[f2];
      fb2 += wrow[f2] * a2[8 + f2];
    }
    f1b[i] = fb1; f2b[i] = fb2;
  }
  __syncthreads();
  if (tid < NN) {
    const int i = tid;
    const float fi = f1b[i];
    float m = -1e30f;
    for (int j = 0; j < NN; ++j)
      if (adjm[i * 129 + j] != 0.f)
        m = fmaxf(m, lrelu(fi + f2b[j]));
    float ssum = 0.f;
    float o[8];
#pragma unroll
    for (int f2 = 0; f2 < 8; ++f2) o[f2] = 0.f;
    for (int j = 0; j < NN; ++j)
      if (adjm[i * 129 + j] != 0.f) {
        const float wgt = __expf(lrelu(fi + f2b[j]) - m);
        ssum += wgt;
#pragma unroll
        for (int f2 = 0; f2 < 8; ++f2) o[f2] += wgt * Wh2[j][f2];
      }
    const float inv = 1.f / ssum;
#pragma unroll
    for (int f2 = 0; f2 < 8; ++f2)
      xg_out[b * (NN * 8) + i * 8 + f2] = o[f2] * inv;
  }
}

// ---------------------------------------------------------------------------
// lstm_heads: 3-group quad-butterfly 2-layer LSTM scan + fused heads.
// 4 blocks x 768 threads (12 waves = exactly 3/EU).
//   group0 (waves 0-3):  Whh0 slice -> L0 gates, owns c0, writes h0[t]
//   group1 (waves 4-7):  Wih1 slice -> L1 ih-partials -> P1[t] (dbuf)
//   group2 (waves 8-11): Whh1 slice + P1[t-1] + bias -> L1 step t-2, owns c1
// ONE barrier/step (grp2 consumes P1 one iteration late; 514 iterations).
// amdgpu_waves_per_eu(3,3): the MAX is the binding knob — R5's
// __launch_bounds__(768,3) sets only the min and the scheduler targeted
// 8 waves/EU (VGPR=56, weights reloaded every step). max=3 raises the
// pressure budget to 512/3=170 >> demand (~100) -> weights stay resident,
// and min=3 guarantees alloc <= 170 so the 12-wave launch always fits.
// ---------------------------------------------------------------------------
__global__ __attribute__((amdgpu_flat_work_group_size(768, 768),
                          amdgpu_waves_per_eu(3, 3)))
void lstm_heads(
    const float* __restrict__ X0T, const float* __restrict__ Whh0,
    const float* __restrict__ Wih1, const float* __restrict__ Whh1,
    const float* __restrict__ bih1, const float* __restrict__ bhh1,
    const float* __restrict__ xg,
    const float* __restrict__ dw1, const float* __restrict__ db1,
    const float* __restrict__ dw2, const float* __restrict__ db2,
    const float* __restrict__ rw1, const float* __restrict__ rb1,
    const float* __restrict__ rw2, const float* __restrict__ rb2,
    const float* __restrict__ vw1, const float* __restrict__ vb1,
    const float* __restrict__ vw2, const float* __restrict__ vb2,
    float* __restrict__ out)
{
  const int b   = blockIdx.x;
  const int t   = threadIdx.x;
  const int grp = t >> 8;            // 0,1,2 (wave-aligned)
  const int r   = t & 255;           // == uu*4 + q2
  const int uu  = r >> 2, q2 = r & 3;

  __shared__ __align__(16) float hb[2][2][HID];   // [buf][layer][unit]
  __shared__ __align__(16) float P1[2][G4];       // dbuf ih-partials
  __shared__ float cbuf[1088];
  __shared__ float hidc[96];

  const float* Wsrc = (grp == 0) ? Whh0 : (grp == 1) ? Wih1 : Whh1;
  float4 w[4][4];
#pragma unroll
  for (int j = 0; j < 4; ++j) {
    const int row = (uu + 64 * j) * HID + 16 * q2;
#pragma unroll
    for (int c = 0; c < 4; ++c)
      w[j][c] = *reinterpret_cast<const float4*>(Wsrc + row + 4 * c);
    pin4(w[j][0]); pin4(w[j][1]); pin4(w[j][2]); pin4(w[j][3]);
  }
  float4 b1v = make_float4(0.f, 0.f, 0.f, 0.f);
  if (grp == 2) {
    b1v.x = bih1[uu]       + bhh1[uu];
    b1v.y = bih1[uu + 64]  + bhh1[uu + 64];
    b1v.z = bih1[uu + 128] + bhh1[uu + 128];
    b1v.w = bih1[uu + 192] + bhh1[uu + 192];
  }

  if (t < 256) reinterpret_cast<float*>(hb)[t] = 0.f;   // both buffers
  float cst = 0.f;                    // c0 (grp0) / c1 (grp2), per-quad redundant
  const float* X0b = X0T + b * G4 + uu * 4;
  float4 cur = make_float4(0.f, 0.f, 0.f, 0.f);
  if (grp == 0) cur = *reinterpret_cast<const float4*>(X0b);
  __syncthreads();

  // Pipeline (iter TT): grp0 -> h0[TT]; grp1 -> P1[TT] = Wih1*h0[TT-1];
  // grp2 -> L1 step TT-2 (reads P1[TT-1], h1[TT-3]) -> h1[TT-2].
#define LSTM_STEP(TT, RB, WB)                                                  \
  do {                                                                         \
    const float4* hp = reinterpret_cast<const float4*>(                        \
        (grp == 2) ? &hb[RB][1][0] : &hb[RB][0][0]);                           \
    float4 hq[4];                                                              \
    hq[0] = hp[4 * q2 + 0]; hq[1] = hp[4 * q2 + 1];                            \
    hq[2] = hp[4 * q2 + 2]; hq[3] = hp[4 * q2 + 3];                            \
    float4 p1v = make_float4(0.f, 0.f, 0.f, 0.f);                              \
    if (grp == 2) p1v = *reinterpret_cast<const float4*>(&P1[1 - (RB)][uu * 4]); \
    float4 nxt = cur;                                                          \
    if (grp == 0 && (TT) + 1 < SEQ)                                            \
      nxt = *reinterpret_cast<const float4*>(X0b + ((TT) + 1) * (BATCH * G4)); \
    float A0 = dotacc(w[0], hq, 0.f);                                          \
    float A1 = dotacc(w[1], hq, 0.f);                                          \
    float A2 = dotacc(w[2], hq, 0.f);                                          \
    float A3 = dotacc(w[3], hq, 0.f);                                          \
    const float S0 = qsum(A0), S1 = qsum(A1), S2 = qsum(A2), S3 = qsum(A3);    \
    if (grp == 0) {                                                            \
      if ((TT) < SEQ) {                                                        \
        const float gi = fsigm(S0 + cur.x);                                    \
        const float gf = fsigm(S1 + cur.y);                                    \
        const float gg = ftanh(S2 + cur.z);                                    \
        const float go = fsigm(S3 + cur.w);                                    \
        cst = fmaf(gf, cst, gi * gg);                                          \
        if (q2 == 0) hb[WB][0][uu] = go * ftanh(cst);                          \
      }                                                                        \
    } else if (grp == 1) {                                                     \
      if ((TT) >= 1 && (TT) <= SEQ) {                                          \
        const float sel = (q2 == 0) ? S0 : (q2 == 1) ? S1 : (q2 == 2) ? S2 : S3; \
        P1[RB][r] = sel;                                                       \
      }                                                                        \
    } else {                                                                   \
      if ((TT) >= 2) {                                                         \
        const float gi = fsigm(S0 + p1v.x + b1v.x);                            \
        const float gf = fsigm(S1 + p1v.y + b1v.y);                            \
        const float gg = ftanh(S2 + p1v.z + b1v.z);                            \
        const float go = fsigm(S3 + p1v.w + b1v.w);                            \
        cst = fmaf(gf, cst, gi * gg);                                          \
        if (q2 == 0) hb[WB][1][uu] = go * ftanh(cst);                          \
      }                                                                        \
    }                                                                          \
    cur = nxt;                                                                 \
    __syncthreads();                                                           \
  } while (0)

  for (int tt = 0; tt < SEQ + 2; tt += 2) {   // 514 iterations total
    LSTM_STEP(tt, 0, 1);
    LSTM_STEP(tt + 1, 1, 0);
  }
#undef LSTM_STEP
  // grp2's last write (TT=513, WB=0): hb[0][1][*] = h1[SEQ-1] = xl_out.

  // ---------------- fused heads: c = [h1(64) | xg_b(1024)] ----------------
  if (t < 64) cbuf[t] = hb[0][1][t];
  for (int k = t; k < 1024; k += 768) cbuf[64 + k] = xg[b * 1024 + k];
  __syncthreads();
  if (t < 96) {
    const int head = t >> 5, h = t & 31;
    const float* w1 = (head == 0) ? dw1 : (head == 1) ? rw1 : vw1;
    const float* b1 = (head == 0) ? db1 : (head == 1) ? rb1 : vb1;
    float a0 = 0.f, a1v = 0.f, a2v = 0.f, a3v = 0.f;
    for (int k = 0; k < 1088; k += 4) {
      a0  = fmaf(cbuf[k],     w1[k * 32 + h],       a0);
      a1v = fmaf(cbuf[k + 1], w1[(k + 1) * 32 + h], a1v);
      a2v = fmaf(cbuf[k + 2], w1[(k + 2) * 32 + h], a2v);
      a3v = fmaf(cbuf[k + 3], w1[(k + 3) * 32 + h], a3v);
    }
    hidc[head * 32 + h] = fmaxf(b1[h] + ((a0 + a1v) + (a2v + a3v)), 0.f);
  }
  __syncthreads();
  if (t < 4) {
    const int head2 = (t < 2) ? t : 2;
    const int o = (t < 2) ? 0 : (t - 2);
    const int odim = (t < 2) ? 1 : 2;
    const float* w2  = (head2 == 0) ? dw2 : (head2 == 1) ? rw2 : vw2;
    const float* b2p = (head2 == 0) ? db2 : (head2 == 1) ? rb2 : vb2;
    float acc = b2p[o];
    for (int hh = 0; hh < 32; ++hh)
      acc = fmaf(hidc[head2 * 32 + hh], w2[hh * odim + o], acc);
    const int off = (t == 0) ? b : (t == 1) ? (4 + b) : (8 + 2 * b + o);
    out[off] = acc;   // [dir(4) | ret(4) | vol(4x2)] flat
  }
}

// ---------------------------------------------------------------------------
extern "C" void kernel_launch(void* const* d_in, const int* in_sizes, int n_in,
                              void* d_out, int out_size, void* d_ws, size_t ws_size,
                              hipStream_t stream) {
  const float* x     = (const float*)d_in[0];
  const int*   adj   = (const int*)  d_in[1];
  const float* emb_w = (const float*)d_in[2];
  const float* emb_b = (const float*)d_in[3];
  const float* g1W   = (const float*)d_in[4];
  const float* g1a   = (const float*)d_in[5];
  const float* g2W   = (const float*)d_in[6];
  const float* g2a   = (const float*)d_in[7];
  const float* Wih0  = (const float*)d_in[8];
  const float* Whh0  = (const float*)d_in[9];
  const float* bih0  = (const float*)d_in[10];
  const float* bhh0  = (const float*)d_in[11];
  const float* Wih1  = (const float*)d_in[12];
  const float* Whh1  = (const float*)d_in[13];
  const float* bih1  = (const float*)d_in[14];
  const float* bhh1  = (const float*)d_in[15];
  const float* dw1 = (const float*)d_in[16]; const float* db1 = (const float*)d_in[17];
  const float* dw2 = (const float*)d_in[18]; const float* db2 = (const float*)d_in[19];
  const float* rw1 = (const float*)d_in[20]; const float* rb1 = (const float*)d_in[21];
  const float* rw2 = (const float*)d_in[22]; const float* rb2 = (const float*)d_in[23];
  const float* vw1 = (const float*)d_in[24]; const float* vb1 = (const float*)d_in[25];
  const float* vw2 = (const float*)d_in[26]; const float* vb2 = (const float*)d_in[27];

  float* ws = (float*)d_ws;
  float* X0 = ws;                         // SEQ*BATCH*256 floats = 2 MB (transposed)
  float* xg = ws + SEQ * BATCH * G4;      // 4096 floats
  float* out = (float*)d_out;

  hipLaunchKernelGGL(prep_kernel, dim3(132), dim3(512), 0, stream,
                     x, Wih0, bih0, bhh0, X0,
                     adj, emb_w, emb_b, g1W, g1a, g2W, g2a, xg);
  hipLaunchKernelGGL(lstm_heads, dim3(BATCH), dim3(768), 0, stream,
                     X0, Whh0, Wih1, Whh1, bih1, bhh1, xg,
                     dw1, db1, dw2, db2, rw1, rb1, rw2, rb2,
                     vw1, vb1, vw2, vb2, out);
}